// Round 2
// baseline (239.651 us; speedup 1.0000x reference)
//
#include <hip/hip_runtime.h>
#include <hip/hip_bf16.h>

// ---- types ------------------------------------------------------------
typedef short short8 __attribute__((ext_vector_type(8)));   // 8 bf16 MFMA A/B frag
typedef float f32x4  __attribute__((ext_vector_type(4)));   // MFMA C/D frag (16x16)
typedef float f32x16 __attribute__((ext_vector_type(16)));  // MFMA C/D frag (32x32)
typedef unsigned int u32x4 __attribute__((ext_vector_type(4))); // 16B vehicle

union V16   { u32x4 v; short8 s; };
union U16x8 { u32x4 v; unsigned short u[8]; };
union FB4   { u32x4 v; float f[4]; };
union BF2U  { __hip_bfloat162 h; unsigned int u; };

__device__ inline unsigned short f2bf(float f) {
  union { float f; unsigned int u; } x; x.f = f;
  unsigned int u = x.u + 0x7fffu + ((x.u >> 16) & 1u);   // RNE
  return (unsigned short)(u >> 16);
}

__device__ __forceinline__ unsigned int pkbf(float a, float b) {
  BF2U p; p.h = __float22bfloat162_rn(make_float2(a, b)); return p.u;
}

// v_permlane32_swap_b32: a'[0:31]=a[0:31], a'[32:63]=b[0:31],
//                        b'[0:31]=a[32:63], b'[32:63]=b[32:63]
__device__ __forceinline__ void plswap(unsigned int& a, unsigned int& b) {
  asm("v_permlane32_swap_b32 %0, %1" : "+v"(a), "+v"(b));
}

// fp32-vs-bf16 input detection from hs's first 64 even u16 words
__device__ __forceinline__ int probe_fp32(const unsigned short* hs) {
  int bad = 0;
#pragma unroll
  for (int i = 0; i < 64; ++i) {
    unsigned int e = (hs[2 * i] >> 7) & 0xFFu;
    if (e >= 0xFEu || (e > 0u && e < 0x60u)) bad++;
  }
  return bad >= 6;
}

// async global->LDS DMA, 16B/lane; LDS dest = wave-uniform base + lane*16
__device__ __forceinline__ void gl_lds16(const unsigned short* g, unsigned short* l) {
  __builtin_amdgcn_global_load_lds(
      (const __attribute__((address_space(1))) unsigned int*)g,
      (__attribute__((address_space(3))) unsigned int*)l, 16, 0, 0);
}

#define PIN() __builtin_amdgcn_sched_barrier(0)

// ---- weights transpose (z=0..3) + hs convert (z=4), one dispatch ------
__global__ __launch_bounds__(256) void w_tr(const void* __restrict__ Wq,
                                            const void* __restrict__ Wk,
                                            const void* __restrict__ Wv,
                                            const void* __restrict__ Wo,
                                            const void* __restrict__ hs,
                                            unsigned short* __restrict__ WT,
                                            unsigned short* __restrict__ WoT,
                                            unsigned short* __restrict__ hsb) {
  __shared__ unsigned short t[32][33];
  __shared__ int sf;
  if (threadIdx.x == 0) sf = probe_fp32((const unsigned short*)hs);
  __syncthreads();
  const int f = sf;
  const int z = blockIdx.z;
  if (z == 4) {                            // hs convert path
    size_t i0 = ((size_t)(blockIdx.y * 48 + blockIdx.x) * 256 + threadIdx.x) * 8;
    if (f) {
      const float* in = (const float*)hs;
      FB4 a, b; a.v = *(const u32x4*)&in[i0]; b.v = *(const u32x4*)&in[i0 + 4];
      U16x8 p;
#pragma unroll
      for (int j = 0; j < 4; ++j) { p.u[j] = f2bf(a.f[j]); p.u[j + 4] = f2bf(b.f[j]); }
      *(u32x4*)&hsb[i0] = p.v;
    } else {
      *(u32x4*)&hsb[i0] = *(const u32x4*)((const unsigned short*)hs + i0);
    }
    return;
  }
  if (blockIdx.y >= 48) return;            // transpose paths: 48x48 grid
  const void* in_; unsigned short* out; int C;
  if      (z == 0) { in_ = Wq; out = WT;              C = 192;  }
  else if (z == 1) { in_ = Wk; out = WT + 192 * 1536; C = 192;  }
  else if (z == 2) { in_ = Wv; out = WT + 384 * 1536; C = 1536; }
  else             { in_ = Wo; out = WoT;             C = 1536; }
  const int c0 = blockIdx.x * 32;
  if (c0 >= C) return;                     // uniform early exit
  const int tx = threadIdx.x & 31, ty = threadIdx.x >> 5;
  const int r0 = blockIdx.y * 32;          // R = 1536 rows for all four
#pragma unroll
  for (int i = 0; i < 4; ++i) {
    size_t idx = (size_t)(r0 + ty + 8 * i) * C + (c0 + tx);
    t[ty + 8 * i][tx] = f ? f2bf(((const float*)in_)[idx])
                          : ((const unsigned short*)in_)[idx];
  }
  __syncthreads();
#pragma unroll
  for (int i = 0; i < 4; ++i)
    out[(size_t)(c0 + ty + 8 * i) * 1536 + (r0 + tx)] = t[tx][ty + 8 * i];
}

// ---- v transpose: out[z][c][r] = in[z][r][c] (internal bf16) ----------
__global__ __launch_bounds__(256) void tr_v(const unsigned short* __restrict__ in_,
                                            unsigned short* __restrict__ out,
                                            int R, int C, int ldin,
                                            long long in_bstride, long long out_bstride) {
  __shared__ unsigned short t[32][33];
  const size_t ibase = (size_t)blockIdx.z * in_bstride;
  const size_t obase = (size_t)blockIdx.z * out_bstride;
  const int tx = threadIdx.x & 31, ty = threadIdx.x >> 5;
  const int r0 = blockIdx.y * 32, c0 = blockIdx.x * 32;
#pragma unroll
  for (int i = 0; i < 4; ++i)
    t[ty + 8 * i][tx] = in_[ibase + (size_t)(r0 + ty + 8 * i) * ldin + (c0 + tx)];
  __syncthreads();
#pragma unroll
  for (int i = 0; i < 4; ++i)
    out[obase + (size_t)(c0 + ty + 8 * i) * R + (r0 + tx)] = t[tx][ty + 8 * i];
}

// ---- C[M][N] = A[M][K] @ BT[N][K]^T, bf16 — 8-wave 4-phase ring-3 ------
// Round-12: BM=256 x BN=128, BK=64, 512 threads (8 waves, 4M x 2N, 64x64
// wave tiles — frag math identical to the proven 2-phase kernel). 3-deep
// LDS ring (144 KB) gives depth-2 prefetch so the per-K-tile boundary wait
// is a COUNTED s_waitcnt vmcnt(6) — tile t+2's loads stay in flight across
// the barrier (T4). Each K-tile = 4 quadrant phases of {ds_read frags ||
// 2 x global_load_lds -> barrier -> setprio(1) 8 MFMA setprio(0) ->
// barrier} (T3+T5). sched_barrier(0) pins every phase boundary: also a
// correctness requirement, since buf[(t+2)%3] == buf[(t-1)%3] (WAR).
__global__ __launch_bounds__(512, 2) void gemm8(const unsigned short* __restrict__ A,
                                                const unsigned short* __restrict__ BT,
                                                void* __restrict__ C_,
                                                int M, int N, int K,
                                                const unsigned short* __restrict__ probe_src) {
  __shared__ unsigned short As[3][256][64];   // 96 KB
  __shared__ unsigned short Bs[3][128][64];   // 48 KB
  const int m0 = blockIdx.y * 256, n0 = blockIdx.x * 128;
  const int tid = threadIdx.x;
  const int lane = tid & 63, w = tid >> 6;     // w 0..7
  const int wr = w >> 1, wc = w & 1;           // wave tile (64x64) @ (wr*64, wc*64)
  const int quad = lane >> 4, mrow = lane & 15;
  const int fsw = (mrow & 7);                  // frag-read swizzle

  const int sr = lane >> 3;                    // staging row-in-8
  const int sc = ((lane & 7) ^ sr) * 8;        // swizzled global chunk (shorts)
  // A rows j=0..3: 32w+8j+sr (0..255); B rows j=0..1: 16w+8j+sr (0..127)
  const unsigned short* Ab = A  + (size_t)(m0 + 32 * w + sr) * K + sc;
  const unsigned short* Bb = BT + (size_t)(n0 + 16 * w + sr) * K + sc;

#define STAGE_A(T2, J) gl_lds16(Ab + (size_t)(8 * (J)) * K + (size_t)(T2) * 64, \
                                &As[(T2) % 3][32 * w + 8 * (J)][0])
#define STAGE_B(T2, J) gl_lds16(Bb + (size_t)(8 * (J)) * K + (size_t)(T2) * 64, \
                                &Bs[(T2) % 3][16 * w + 8 * (J)][0])
#define RD_A(dst, mt, kq) { V16 u_; u_.v = *(const u32x4*)&As[cur][wr * 64 + (mt) * 16 + mrow][(((kq) * 4 + quad) ^ fsw) * 8]; dst = u_.s; }
#define RD_B(dst, nt, kq) { V16 u_; u_.v = *(const u32x4*)&Bs[cur][wc * 64 + (nt) * 16 + mrow][(((kq) * 4 + quad) ^ fsw) * 8]; dst = u_.s; }

  const f32x4 zf = {0.f, 0.f, 0.f, 0.f};
  f32x4 acc[4][4];
#pragma unroll
  for (int mt = 0; mt < 4; ++mt)
#pragma unroll
    for (int nt = 0; nt < 4; ++nt) acc[mt][nt] = zf;

  const int nk = K >> 6;                       // BK=64 tiles (24 here)

  // prologue: stage tiles 0 and 1; wait tile 0 (6 of 12 outstanding)
#pragma unroll
  for (int j = 0; j < 4; ++j) STAGE_A(0, j);
#pragma unroll
  for (int j = 0; j < 2; ++j) STAGE_B(0, j);
#pragma unroll
  for (int j = 0; j < 4; ++j) STAGE_A(1, j);
#pragma unroll
  for (int j = 0; j < 2; ++j) STAGE_B(1, j);
  asm volatile("s_waitcnt vmcnt(6)" ::: "memory");
  PIN();
  __builtin_amdgcn_s_barrier();
  PIN();

  for (int t = 0; t < nk; ++t) {
    const int cur = t % 3;
    const int t2 = t + 2;
    const bool st = t2 < nk;
    short8 a0, a1, a2, a3, b0, b1, b2, b3;

    // ---- phase 0: frags (kq0: mt0,1 + all B) | stage A j0,j1 of t+2
    RD_A(a0, 0, 0); RD_A(a1, 1, 0);
    RD_B(b0, 0, 0); RD_B(b1, 1, 0); RD_B(b2, 2, 0); RD_B(b3, 3, 0);
    if (st) { STAGE_A(t2, 0); STAGE_A(t2, 1); }
    PIN(); __builtin_amdgcn_s_barrier(); PIN();
    __builtin_amdgcn_s_setprio(1);
    acc[0][0] = __builtin_amdgcn_mfma_f32_16x16x32_bf16(a0, b0, acc[0][0], 0, 0, 0);
    acc[0][1] = __builtin_amdgcn_mfma_f32_16x16x32_bf16(a0, b1, acc[0][1], 0, 0, 0);
    acc[0][2] = __builtin_amdgcn_mfma_f32_16x16x32_bf16(a0, b2, acc[0][2], 0, 0, 0);
    acc[0][3] = __builtin_amdgcn_mfma_f32_16x16x32_bf16(a0, b3, acc[0][3], 0, 0, 0);
    acc[1][0] = __builtin_amdgcn_mfma_f32_16x16x32_bf16(a1, b0, acc[1][0], 0, 0, 0);
    acc[1][1] = __builtin_amdgcn_mfma_f32_16x16x32_bf16(a1, b1, acc[1][1], 0, 0, 0);
    acc[1][2] = __builtin_amdgcn_mfma_f32_16x16x32_bf16(a1, b2, acc[1][2], 0, 0, 0);
    acc[1][3] = __builtin_amdgcn_mfma_f32_16x16x32_bf16(a1, b3, acc[1][3], 0, 0, 0);
    __builtin_amdgcn_s_setprio(0);
    PIN(); __builtin_amdgcn_s_barrier(); PIN();

    // ---- phase 1: frags (kq0: mt2,3) | stage A j2,j3
    RD_A(a2, 2, 0); RD_A(a3, 3, 0);
    if (st) { STAGE_A(t2, 2); STAGE_A(t2, 3); }
    PIN(); __builtin_amdgcn_s_barrier(); PIN();
    __builtin_amdgcn_s_setprio(1);
    acc[2][0] = __builtin_amdgcn_mfma_f32_16x16x32_bf16(a2, b0, acc[2][0], 0, 0, 0);
    acc[2][1] = __builtin_amdgcn_mfma_f32_16x16x32_bf16(a2, b1, acc[2][1], 0, 0, 0);
    acc[2][2] = __builtin_amdgcn_mfma_f32_16x16x32_bf16(a2, b2, acc[2][2], 0, 0, 0);
    acc[2][3] = __builtin_amdgcn_mfma_f32_16x16x32_bf16(a2, b3, acc[2][3], 0, 0, 0);
    acc[3][0] = __builtin_amdgcn_mfma_f32_16x16x32_bf16(a3, b0, acc[3][0], 0, 0, 0);
    acc[3][1] = __builtin_amdgcn_mfma_f32_16x16x32_bf16(a3, b1, acc[3][1], 0, 0, 0);
    acc[3][2] = __builtin_amdgcn_mfma_f32_16x16x32_bf16(a3, b2, acc[3][2], 0, 0, 0);
    acc[3][3] = __builtin_amdgcn_mfma_f32_16x16x32_bf16(a3, b3, acc[3][3], 0, 0, 0);
    __builtin_amdgcn_s_setprio(0);
    PIN(); __builtin_amdgcn_s_barrier(); PIN();

    // ---- phase 2: frags (kq1: mt0,1 + all B) | stage B j0,j1
    RD_A(a0, 0, 1); RD_A(a1, 1, 1);
    RD_B(b0, 0, 1); RD_B(b1, 1, 1); RD_B(b2, 2, 1); RD_B(b3, 3, 1);
    if (st) { STAGE_B(t2, 0); STAGE_B(t2, 1); }
    PIN(); __builtin_amdgcn_s_barrier(); PIN();
    __builtin_amdgcn_s_setprio(1);
    acc[0][0] = __builtin_amdgcn_mfma_f32_16x16x32_bf16(a0, b0, acc[0][0], 0, 0, 0);
    acc[0][1] = __builtin_amdgcn_mfma_f32_16x16x32_bf16(a0, b1, acc[0][1], 0, 0, 0);
    acc[0][2] = __builtin_amdgcn_mfma_f32_16x16x32_bf16(a0, b2, acc[0][2], 0, 0, 0);
    acc[0][3] = __builtin_amdgcn_mfma_f32_16x16x32_bf16(a0, b3, acc[0][3], 0, 0, 0);
    acc[1][0] = __builtin_amdgcn_mfma_f32_16x16x32_bf16(a1, b0, acc[1][0], 0, 0, 0);
    acc[1][1] = __builtin_amdgcn_mfma_f32_16x16x32_bf16(a1, b1, acc[1][1], 0, 0, 0);
    acc[1][2] = __builtin_amdgcn_mfma_f32_16x16x32_bf16(a1, b2, acc[1][2], 0, 0, 0);
    acc[1][3] = __builtin_amdgcn_mfma_f32_16x16x32_bf16(a1, b3, acc[1][3], 0, 0, 0);
    __builtin_amdgcn_s_setprio(0);
    PIN(); __builtin_amdgcn_s_barrier(); PIN();

    // ---- phase 3: frags (kq1: mt2,3) | counted boundary wait
    RD_A(a2, 2, 1); RD_A(a3, 3, 1);
    PIN(); __builtin_amdgcn_s_barrier(); PIN();
    __builtin_amdgcn_s_setprio(1);
    acc[2][0] = __builtin_amdgcn_mfma_f32_16x16x32_bf16(a2, b0, acc[2][0], 0, 0, 0);
    acc[2][1] = __builtin_amdgcn_mfma_f32_16x16x32_bf16(a2, b1, acc[2][1], 0, 0, 0);
    acc[2][2] = __builtin_amdgcn_mfma_f32_16x16x32_bf16(a2, b2, acc[2][2], 0, 0, 0);
    acc[2][3] = __builtin_amdgcn_mfma_f32_16x16x32_bf16(a2, b3, acc[2][3], 0, 0, 0);
    acc[3][0] = __builtin_amdgcn_mfma_f32_16x16x32_bf16(a3, b0, acc[3][0], 0, 0, 0);
    acc[3][1] = __builtin_amdgcn_mfma_f32_16x16x32_bf16(a3, b1, acc[3][1], 0, 0, 0);
    acc[3][2] = __builtin_amdgcn_mfma_f32_16x16x32_bf16(a3, b2, acc[3][2], 0, 0, 0);
    acc[3][3] = __builtin_amdgcn_mfma_f32_16x16x32_bf16(a3, b3, acc[3][3], 0, 0, 0);
    __builtin_amdgcn_s_setprio(0);
    if (st) asm volatile("s_waitcnt vmcnt(6)" ::: "memory");  // t+1 landed; t+2 in flight
    else    asm volatile("s_waitcnt vmcnt(0)" ::: "memory");  // tail drain
    PIN(); __builtin_amdgcn_s_barrier(); PIN();
  }

  const int of = probe_src ? probe_fp32(probe_src) : 0;
#pragma unroll
  for (int mt = 0; mt < 4; ++mt)
#pragma unroll
    for (int nt = 0; nt < 4; ++nt)
#pragma unroll
      for (int r = 0; r < 4; ++r) {
        int grow = m0 + wr * 64 + mt * 16 + quad * 4 + r;
        int gcol = n0 + wc * 64 + nt * 16 + mrow;
        size_t idx = (size_t)grow * N + gcol;
        if (of) ((float*)C_)[idx] = acc[mt][nt][r];
        else    ((unsigned short*)C_)[idx] = f2bf(acc[mt][nt][r]);
      }
#undef STAGE_A
#undef STAGE_B
#undef RD_A
#undef RD_B
}

// ---- fused causal "based" attention — 32x32 swapped-QK^T (unchanged) ---
__global__ __launch_bounds__(256, 3) void attn_based(const unsigned short* __restrict__ qkv,
                                                     const unsigned short* __restrict__ vT,
                                                     unsigned short* __restrict__ obuf) {
  __shared__ unsigned short Vs[2][128][64];  // [buf][hd][kv] bf16, 32 KB (DMA dest)
  __shared__ float zbuf[2][32];
  const int LD = 1920;
  const int bh = blockIdx.x;
  const int qt = 31 - blockIdx.y;            // long blocks dispatch first (LPT)
  const int b = bh / 12, h = bh % 12;
  const int tid = threadIdx.x;
  const int lane = tid & 63, w = tid >> 6;
  const int qsub = w & 1, kvp = w >> 1;      // q-subtile / kv-parity of this wave
  const int col = lane & 31, hi = lane >> 5;

  const int q0 = qt * 64 + qsub * 32;        // wave's q block start (abs)
  const int q_abs = q0 + col;

  // Q B-frag (loop-invariant): B[k=f][n=q]: lane holds q=col, f=hi*8+j
  V16 bq; bq.v = *(const u32x4*)&qkv[(size_t)(b * 2048 + q_abs) * LD + h * 16 + hi * 8];

  // K A-frag: A[m=kv][k=f]: lane holds kv=col (+kv0), f=hi*8+j
  const unsigned short* kptr =
      &qkv[(size_t)(b * 2048 + kvp * 32 + col) * LD + 192 + h * 16 + hi * 8];

  const unsigned short* vbase = vT + (size_t)(bh * 128) * 2048;

  const f32x16 z16 = {0.f,0.f,0.f,0.f,0.f,0.f,0.f,0.f,0.f,0.f,0.f,0.f,0.f,0.f,0.f,0.f};
  f32x16 oacc[4];                            // [hd-chunk of 32]
#pragma unroll
  for (int nc = 0; nc < 4; ++nc) oacc[nc] = z16;
  float zcA[4] = {0.f, 0.f, 0.f, 0.f};       // split z chains (merged at end)

#define STAGE_V(KV0, BUF)                                                     \
  {                                                                           \
    _Pragma("unroll")                                                         \
    for (int j = 0; j < 4; ++j) {                                             \
      const int row = 32 * w + 8 * j + (lane >> 3);                           \
      gl_lds16(vbase + (size_t)row * 2048 + (KV0) + ((lane & 7) ^ (lane >> 3)) * 8, \
               &Vs[BUF][32 * w + 8 * j][0]);                                  \
    }                                                                         \
  }

  STAGE_V(0, 0);
  V16 kf; kf.v = *(const u32x4*)kptr;        // K frag for tile 0
  __syncthreads();

  for (int t = 0; t <= qt; ++t) {
    const int cur = t & 1;
    if (t < qt) STAGE_V((t + 1) * 64, cur ^ 1);

    V16 kfn;
    kptr += (size_t)64 * LD;
    if (t < qt) kfn.v = *(const u32x4*)kptr;   // prefetch next K frag

    // wave-uniform: does this wave's kv sub-block exist under the causal mask?
    const bool live = (t < qt) | (kvp <= qsub);
    if (live) {
      // S^T[kv][q] in one MFMA: col = lane&31 = q, row kv = (r&3)+8*(r>>2)+4*hi
      f32x16 st = __builtin_amdgcn_mfma_f32_32x32x16_bf16(kf.s, bq.s, z16, 0, 0, 0);
      const int kv0 = t * 64 + kvp * 32;
      const bool diag = (t == qt) & (kvp == qsub);
      float pr[16];
      if (diag) {
#pragma unroll
        for (int r = 0; r < 16; ++r) {
          float s = st[r];
          float a = fmaf(s, fmaf(s, 0.03125f, 0.25f), 1.0f);
          const int kvr = kv0 + (r & 3) + 8 * (r >> 2) + 4 * hi;
          a = (kvr <= q_abs) ? a : 0.0f;
          zcA[r & 3] += a; pr[r] = a;
        }
      } else {
#pragma unroll
        for (int r = 0; r < 16; ++r) {
          float s = st[r];
          float a = fmaf(s, fmaf(s, 0.03125f, 0.25f), 1.0f);
          zcA[r & 3] += a; pr[r] = a;
        }
      }

      // P -> two PV A-frags (kv 0..15 / 16..31) via cvt_pk + permlane32_swap
      union PA { short8 s; unsigned int wd[4]; } pa0, pa1;
      {
        unsigned int x0 = pkbf(pr[0], pr[1]), x1 = pkbf(pr[2], pr[3]);
        unsigned int y0 = pkbf(pr[4], pr[5]), y1 = pkbf(pr[6], pr[7]);
        plswap(x0, y0); plswap(x1, y1);
        pa0.wd[0] = x0; pa0.wd[1] = x1; pa0.wd[2] = y0; pa0.wd[3] = y1;
      }
      {
        unsigned int x0 = pkbf(pr[8], pr[9]),  x1 = pkbf(pr[10], pr[11]);
        unsigned int y0 = pkbf(pr[12], pr[13]), y1 = pkbf(pr[14], pr[15]);
        plswap(x0, y0); plswap(x1, y1);
        pa1.wd[0] = x0; pa1.wd[1] = x1; pa1.wd[2] = y0; pa1.wd[3] = y1;
      }

      // PV: B[k=kv][n=hd] frags from swizzled Vs; 8 MFMAs, 2 chained per nc
      __builtin_amdgcn_s_setprio(1);
#pragma unroll
      for (int nc = 0; nc < 4; ++nc) {
        const int hd = nc * 32 + col;
        V16 v0, v1;
        v0.v = *(const u32x4*)&Vs[cur][hd][(((kvp * 4 + hi)     ^ (hd & 7)) * 8)];
        v1.v = *(const u32x4*)&Vs[cur][hd][(((kvp * 4 + 2 + hi) ^ (hd & 7)) * 8)];
        oacc[nc] = __builtin_amdgcn_mfma_f32_32x32x16_bf16(pa0.s, v0.s, oacc[nc], 0, 0, 0);
        oacc[nc] = __builtin_amdgcn_mfma_f32_32x32x16_bf16(pa1.s, v1.s, oacc[nc], 0, 0, 0);
      }
      __builtin_amdgcn_s_setprio(0);
    }
    __syncthreads();   // drains DMA (vmcnt) + guards buffer reuse
    if (t < qt) kf = kfn;
  }

  // z: merge split chains, then lane + lane^32 (rows 4..7 offset half)
  float zcol = (zcA[0] + zcA[1]) + (zcA[2] + zcA[3]);
  zcol += __shfl_xor(zcol, 32, 64);

  // combine kv-parity partials: waves 2,3 donate through LDS (reuse Vs)
  float* fbuf = (float*)&Vs[0][0][0];        // 8192 floats = 32 KB
  if (w >= 2) {
    const int base = (w & 1) * 4096;
#pragma unroll
    for (int nc = 0; nc < 4; ++nc)
#pragma unroll
      for (int g = 0; g < 4; ++g) {
        f32x4 v = {oacc[nc][4 * g], oacc[nc][4 * g + 1],
                   oacc[nc][4 * g + 2], oacc[nc][4 * g + 3]};
        *(f32x4*)&fbuf[base + ((nc * 4 + g) * 64 + lane) * 4] = v;
      }
    if (lane < 32) zbuf[w & 1][lane] = zcol;
  }
  __syncthreads();
  if (w < 2) {
    const int base = w * 4096;
#pragma unroll
    for (int nc = 0; nc < 4; ++nc)
#pragma unroll
      for (int g = 0; g < 4; ++g) {
        f32x4 v = *(const f32x4*)&fbuf[base + ((nc * 4 + g) * 64 + lane) * 4];
#pragma unroll
        for (int r = 0; r < 4; ++r) oacc[nc][4 * g + r] += v[r];
      }
    const float zinv = 1.0f / (zcol + zbuf[w][col] + 1e-12f);
    // D[q][hd]: col = lane&31 = hd-offset, row q = (r&3)+8*(r>>2)+4*hi
#pragma unroll
    for (int g = 0; g < 4; ++g)
#pragma unroll
      for (int rr = 0; rr < 4; ++rr) {
        const int qrow = rr + 8 * g + 4 * hi;
        const float iv = __shfl(zinv, qrow, 64);
        const size_t base_o = (size_t)(b * 2048 + q0 + qrow) * 1536 + h * 128 + col;
#pragma unroll
        for (int nc = 0; nc < 4; ++nc)
          obuf[base_o + nc * 32] = f2bf(oacc[nc][4 * g + rr] * iv);
      }
  }
#undef STAGE_V
}

// ---- launch -----------------------------------------------------------
extern "C" void kernel_launch(void* const* d_in, const int* in_sizes, int n_in,
                              void* d_out, int out_size, void* d_ws, size_t ws_size,
                              hipStream_t stream) {
  const void* hs = d_in[0];
  const void* Wq = d_in[1];
  const void* Wk = d_in[2];
  const void* Wv = d_in[3];
  const void* Wo = d_in[4];
  const unsigned short* hsp = (const unsigned short*)hs;

  // ws (~51.5 MB): WT[1920][1536] | WoT[1536][1536] | qkvb[4096][1920]
  //                | hsb[4096][1536] | vT[24*128][2048]
  unsigned short* ws   = (unsigned short*)d_ws;
  unsigned short* WT   = ws;                        // q 0..191, k 192..383, v 384..1919
  unsigned short* WoT  = WT + 1920 * 1536;
  unsigned short* qkvb = WoT + 1536 * 1536;
  unsigned short* hsb  = qkvb + 4096 * 1920;
  unsigned short* vT   = hsb + 4096 * 1536;
  unsigned short* obuf = hsb;                       // hsb dead after qkv gemm

  // weights transpose + hs convert, one dispatch
  w_tr<<<dim3(48, 64, 5), 256, 0, stream>>>(Wq, Wk, Wv, Wo, hs, WT, WoT, hsb);

  // fused q|k|v projection: [4096][1536] @ WT^T -> qkvb [4096][1920]
  gemm8<<<dim3(15, 16, 1), 512, 0, stream>>>(hsb, WT, qkvb, 4096, 1920, 1536, nullptr);

  // v columns of qkvb -> per-(b,h) [hd][l]
  tr_v<<<dim3(48, 64, 2), 256, 0, stream>>>(qkvb + 384, vT, 2048, 1536, 1920,
                                            (long long)2048 * 1920, (long long)1536 * 2048);

  // fused causal based-attention (32x32 swapped-QK^T, kv-parity split)
  attn_based<<<dim3(24, 32, 1), 256, 0, stream>>>(qkvb, vT, obuf);

  // output projection -> d_out (fp32 store iff inputs were fp32)
  gemm8<<<dim3(12, 16, 1), 512, 0, stream>>>(obuf, WoT, d_out, 4096, 1536, 1536, hsp);
}

// Round 4
// 207.079 us; speedup vs baseline: 1.1573x; 1.1573x over previous
//
#include <hip/hip_runtime.h>
#include <hip/hip_bf16.h>

// ---- types ------------------------------------------------------------
typedef short short8 __attribute__((ext_vector_type(8)));   // 8 bf16 MFMA A/B frag
typedef float f32x4  __attribute__((ext_vector_type(4)));   // MFMA C/D frag (16x16)
typedef float f32x16 __attribute__((ext_vector_type(16)));  // MFMA C/D frag (32x32)
typedef unsigned int u32x4 __attribute__((ext_vector_type(4))); // 16B vehicle

union V16   { u32x4 v; short8 s; };
union U16x8 { u32x4 v; unsigned short u[8]; };
union FB4   { u32x4 v; float f[4]; };
union BF2U  { __hip_bfloat162 h; unsigned int u; };

__device__ inline unsigned short f2bf(float f) {
  union { float f; unsigned int u; } x; x.f = f;
  unsigned int u = x.u + 0x7fffu + ((x.u >> 16) & 1u);   // RNE
  return (unsigned short)(u >> 16);
}

__device__ __forceinline__ unsigned int pkbf(float a, float b) {
  BF2U p; p.h = __float22bfloat162_rn(make_float2(a, b)); return p.u;
}

// v_permlane32_swap_b32: a'[0:31]=a[0:31], a'[32:63]=b[0:31],
//                        b'[0:31]=a[32:63], b'[32:63]=b[32:63]
__device__ __forceinline__ void plswap(unsigned int& a, unsigned int& b) {
  asm("v_permlane32_swap_b32 %0, %1" : "+v"(a), "+v"(b));
}

// fp32-vs-bf16 input detection from hs's first 64 even u16 words
__device__ __forceinline__ int probe_fp32(const unsigned short* hs) {
  int bad = 0;
#pragma unroll
  for (int i = 0; i < 64; ++i) {
    unsigned int e = (hs[2 * i] >> 7) & 0xFFu;
    if (e >= 0xFEu || (e > 0u && e < 0x60u)) bad++;
  }
  return bad >= 6;
}

// async global->LDS DMA, 16B/lane; LDS dest = wave-uniform base + lane*16
__device__ __forceinline__ void gl_lds16(const unsigned short* g, unsigned short* l) {
  __builtin_amdgcn_global_load_lds(
      (const __attribute__((address_space(1))) unsigned int*)g,
      (__attribute__((address_space(3))) unsigned int*)l, 16, 0, 0);
}

// ---- weights transpose (z=0..3) + hs convert (z=4), one dispatch ------
// z=0: Wq->WT[0:192), z=1: Wk->WT[192:384), z=2: Wv->WT[384:1920), z=3: Wo->WoT
// z=4: hs -> hsb (bf16 contiguous), block idx = y*48+x, 2048 el/block
__global__ __launch_bounds__(256) void w_tr(const void* __restrict__ Wq,
                                            const void* __restrict__ Wk,
                                            const void* __restrict__ Wv,
                                            const void* __restrict__ Wo,
                                            const void* __restrict__ hs,
                                            unsigned short* __restrict__ WT,
                                            unsigned short* __restrict__ WoT,
                                            unsigned short* __restrict__ hsb) {
  __shared__ unsigned short t[32][33];
  __shared__ int sf;
  if (threadIdx.x == 0) sf = probe_fp32((const unsigned short*)hs);
  __syncthreads();
  const int f = sf;
  const int z = blockIdx.z;
  if (z == 4) {                            // hs convert path
    size_t i0 = ((size_t)(blockIdx.y * 48 + blockIdx.x) * 256 + threadIdx.x) * 8;
    if (f) {
      const float* in = (const float*)hs;
      FB4 a, b; a.v = *(const u32x4*)&in[i0]; b.v = *(const u32x4*)&in[i0 + 4];
      U16x8 p;
#pragma unroll
      for (int j = 0; j < 4; ++j) { p.u[j] = f2bf(a.f[j]); p.u[j + 4] = f2bf(b.f[j]); }
      *(u32x4*)&hsb[i0] = p.v;
    } else {
      *(u32x4*)&hsb[i0] = *(const u32x4*)((const unsigned short*)hs + i0);
    }
    return;
  }
  if (blockIdx.y >= 48) return;            // transpose paths: 48x48 grid
  const void* in_; unsigned short* out; int C;
  if      (z == 0) { in_ = Wq; out = WT;              C = 192;  }
  else if (z == 1) { in_ = Wk; out = WT + 192 * 1536; C = 192;  }
  else if (z == 2) { in_ = Wv; out = WT + 384 * 1536; C = 1536; }
  else             { in_ = Wo; out = WoT;             C = 1536; }
  const int c0 = blockIdx.x * 32;
  if (c0 >= C) return;                     // uniform early exit
  const int tx = threadIdx.x & 31, ty = threadIdx.x >> 5;
  const int r0 = blockIdx.y * 32;          // R = 1536 rows for all four
#pragma unroll
  for (int i = 0; i < 4; ++i) {
    size_t idx = (size_t)(r0 + ty + 8 * i) * C + (c0 + tx);
    t[ty + 8 * i][tx] = f ? f2bf(((const float*)in_)[idx])
                          : ((const unsigned short*)in_)[idx];
  }
  __syncthreads();
#pragma unroll
  for (int i = 0; i < 4; ++i)
    out[(size_t)(c0 + ty + 8 * i) * 1536 + (r0 + tx)] = t[tx][ty + 8 * i];
}

// ---- C = A[M][K] @ BT[NB][K]^T, bf16 — proven 2-phase + fused v-transpose
// Round-13 (resubmit; round-3 bench was an infra failure): 2-phase
// structure from round-10/11. For the qkv call, v-column blocks (n0>=384)
// write their C-tile TRANSPOSED into vT[(b*12+h)*128+hd][l] via an LDS
// round-trip in the epilogue (staging buffers dead there) — eliminates the
// tr_v dispatch and ~25 MB HBM traffic. qk columns land compact, ldC=384.
__global__ __launch_bounds__(256) void gemm_bt(const unsigned short* __restrict__ A,
                                               const unsigned short* __restrict__ BT,
                                               void* __restrict__ C_,
                                               int M, int NB, int K, int ldC,
                                               unsigned short* __restrict__ vTout,
                                               const unsigned short* __restrict__ probe_src) {
  __shared__ unsigned short smem[4 * 128 * 64];      // As[2]|Bs[2], 64 KB
#define AS(buf, r, c) smem[(((buf) * 128) + (r)) * 64 + (c)]
#define BS(buf, r, c) smem[(((2 + (buf)) * 128) + (r)) * 64 + (c)]
  const int m0 = blockIdx.y * 128, n0 = blockIdx.x * 128;
  const int tid = threadIdx.x;
  const int lane = tid & 63, w = tid >> 6;
  const int wr = w >> 1, wc = w & 1;
  const int quad = lane >> 4, mrow = lane & 15;

  const int sr = lane >> 3;                          // staging row-in-8
  const int sc = ((lane & 7) ^ (lane >> 3)) * 8;     // swizzled global chunk (shorts)
  const int fsw = (mrow & 7);                        // frag-read swizzle

  const f32x4 zf = {0.f, 0.f, 0.f, 0.f};
  f32x4 acc[4][4];
#pragma unroll
  for (int mt = 0; mt < 4; ++mt)
#pragma unroll
    for (int nt = 0; nt < 4; ++nt) acc[mt][nt] = zf;

  const int nk = K >> 6;                             // BK=64 steps
  // prologue: stage tile 0 into buffer 0 (4 A-loads + 4 B-loads per wave)
#pragma unroll
  for (int j = 0; j < 4; ++j) {
    const int r = 32 * w + 8 * j + sr;
    gl_lds16(&A [(size_t)(m0 + r) * K + sc], &AS(0, 32 * w + 8 * j, 0));
    gl_lds16(&BT[(size_t)(n0 + r) * K + sc], &BS(0, 32 * w + 8 * j, 0));
  }

  for (int ks = 0; ks < nk; ++ks) {
    const int cur = ks & 1;
    __syncthreads();   // drains DMA for buf[cur]; prior reads of buf[cur^1] done
    if (ks + 1 < nk) {
      const int k1 = (ks + 1) << 6;
#pragma unroll
      for (int j = 0; j < 4; ++j) {
        const int r = 32 * w + 8 * j + sr;
        gl_lds16(&A [(size_t)(m0 + r) * K + k1 + sc], &AS(cur ^ 1, 32 * w + 8 * j, 0));
        gl_lds16(&BT[(size_t)(n0 + r) * K + k1 + sc], &BS(cur ^ 1, 32 * w + 8 * j, 0));
      }
    }
#pragma unroll
    for (int kq = 0; kq < 2; ++kq) {
      short8 afr[4], bfr[4];
#pragma unroll
      for (int mt = 0; mt < 4; ++mt) {
        V16 u; u.v = *(const u32x4*)&AS(cur, wr * 64 + mt * 16 + mrow, ((kq * 4 + quad) ^ fsw) * 8);
        afr[mt] = u.s;
      }
#pragma unroll
      for (int nt = 0; nt < 4; ++nt) {
        V16 u; u.v = *(const u32x4*)&BS(cur, wc * 64 + nt * 16 + mrow, ((kq * 4 + quad) ^ fsw) * 8);
        bfr[nt] = u.s;
      }
#pragma unroll
      for (int mt = 0; mt < 4; ++mt)
#pragma unroll
        for (int nt = 0; nt < 4; ++nt)
          acc[mt][nt] = __builtin_amdgcn_mfma_f32_16x16x32_bf16(afr[mt], bfr[nt], acc[mt][nt], 0, 0, 0);
    }
  }

  __syncthreads();                                   // staging LDS now reusable
  if (vTout != nullptr && n0 >= 384) {
    // v-columns: transpose 64x64 wave tile through LDS, store [hd][l]
    unsigned short* T = smem + w * (64 * 72);        // pad 72: 16B-aligned rows
#pragma unroll
    for (int mt = 0; mt < 4; ++mt)
#pragma unroll
      for (int nt = 0; nt < 4; ++nt)
#pragma unroll
        for (int r = 0; r < 4; ++r)
          T[(nt * 16 + mrow) * 72 + mt * 16 + quad * 4 + r] = f2bf(acc[mt][nt][r]);
    asm volatile("s_waitcnt lgkmcnt(0)" ::: "memory");
    const int h  = (n0 - 384) >> 7;                  // head (block-uniform)
    const int gb = (m0 + wr * 64) >> 11;             // batch
    const int l0 = (m0 + wr * 64) & 2047;            // seq offset
    const size_t vrow0 = ((size_t)(gb * 12 + h) << 7) + wc * 64;
#pragma unroll
    for (int i = 0; i < 8; ++i) {
      const int row = (lane >> 3) + 8 * i;           // hd_local 0..63
      const int ch  = (lane & 7) * 8;                // l chunk
      u32x4 vv = *(const u32x4*)&T[row * 72 + ch];
      *(u32x4*)&vTout[(vrow0 + row) * 2048 + l0 + ch] = vv;
    }
  } else {
    const int of = probe_src ? probe_fp32(probe_src) : 0;
#pragma unroll
    for (int mt = 0; mt < 4; ++mt)
#pragma unroll
      for (int nt = 0; nt < 4; ++nt)
#pragma unroll
        for (int r = 0; r < 4; ++r) {
          int grow = m0 + wr * 64 + mt * 16 + quad * 4 + r;
          int gcol = n0 + wc * 64 + nt * 16 + mrow;
          size_t idx = (size_t)grow * ldC + gcol;
          if (of) ((float*)C_)[idx] = acc[mt][nt][r];
          else    ((unsigned short*)C_)[idx] = f2bf(acc[mt][nt][r]);
        }
  }
#undef AS
#undef BS
}

// ---- fused causal "based" attention — 32x32 swapped-QK^T ---------------
// qkv: [4096][384] bf16 (cols 0..191 q, 192..383 k); vT: [24*128][2048]
// obuf: [4096][1536]. grid (24,32): (b*12+h, q-tile of 64). 256 threads.
__global__ __launch_bounds__(256, 3) void attn_based(const unsigned short* __restrict__ qkv,
                                                     const unsigned short* __restrict__ vT,
                                                     unsigned short* __restrict__ obuf) {
  __shared__ unsigned short Vs[2][128][64];  // [buf][hd][kv] bf16, 32 KB (DMA dest)
  __shared__ float zbuf[2][32];
  const int LD = 384;
  const int bh = blockIdx.x;
  const int qt = 31 - blockIdx.y;            // long blocks dispatch first (LPT)
  const int b = bh / 12, h = bh % 12;
  const int tid = threadIdx.x;
  const int lane = tid & 63, w = tid >> 6;
  const int qsub = w & 1, kvp = w >> 1;      // q-subtile / kv-parity of this wave
  const int col = lane & 31, hi = lane >> 5;

  const int q0 = qt * 64 + qsub * 32;        // wave's q block start (abs)
  const int q_abs = q0 + col;

  // Q B-frag (loop-invariant): B[k=f][n=q]: lane holds q=col, f=hi*8+j
  V16 bq; bq.v = *(const u32x4*)&qkv[(size_t)(b * 2048 + q_abs) * LD + h * 16 + hi * 8];

  // K A-frag: A[m=kv][k=f]: lane holds kv=col (+kv0), f=hi*8+j
  const unsigned short* kptr =
      &qkv[(size_t)(b * 2048 + kvp * 32 + col) * LD + 192 + h * 16 + hi * 8];

  const unsigned short* vbase = vT + (size_t)(bh * 128) * 2048;

  const f32x16 z16 = {0.f,0.f,0.f,0.f,0.f,0.f,0.f,0.f,0.f,0.f,0.f,0.f,0.f,0.f,0.f,0.f};
  f32x16 oacc[4];                            // [hd-chunk of 32]
#pragma unroll
  for (int nc = 0; nc < 4; ++nc) oacc[nc] = z16;
  float zcA[4] = {0.f, 0.f, 0.f, 0.f};       // split z chains (merged at end)

#define STAGE_V(KV0, BUF)                                                     \
  {                                                                           \
    _Pragma("unroll")                                                         \
    for (int j = 0; j < 4; ++j) {                                             \
      const int row = 32 * w + 8 * j + (lane >> 3);                           \
      gl_lds16(vbase + (size_t)row * 2048 + (KV0) + ((lane & 7) ^ (lane >> 3)) * 8, \
               &Vs[BUF][32 * w + 8 * j][0]);                                  \
    }                                                                         \
  }

  STAGE_V(0, 0);
  V16 kf; kf.v = *(const u32x4*)kptr;        // K frag for tile 0
  __syncthreads();

  for (int t = 0; t <= qt; ++t) {
    const int cur = t & 1;
    if (t < qt) STAGE_V((t + 1) * 64, cur ^ 1);

    V16 kfn;
    kptr += (size_t)64 * LD;
    if (t < qt) kfn.v = *(const u32x4*)kptr;   // prefetch next K frag

    // wave-uniform: does this wave's kv sub-block exist under the causal mask?
    const bool live = (t < qt) | (kvp <= qsub);
    if (live) {
      // S^T[kv][q] in one MFMA: col = lane&31 = q, row kv = (r&3)+8*(r>>2)+4*hi
      f32x16 st = __builtin_amdgcn_mfma_f32_32x32x16_bf16(kf.s, bq.s, z16, 0, 0, 0);
      const int kv0 = t * 64 + kvp * 32;
      const bool diag = (t == qt) & (kvp == qsub);
      float pr[16];
      if (diag) {
#pragma unroll
        for (int r = 0; r < 16; ++r) {
          float s = st[r];
          float a = fmaf(s, fmaf(s, 0.03125f, 0.25f), 1.0f);
          const int kvr = kv0 + (r & 3) + 8 * (r >> 2) + 4 * hi;
          a = (kvr <= q_abs) ? a : 0.0f;
          zcA[r & 3] += a; pr[r] = a;
        }
      } else {
#pragma unroll
        for (int r = 0; r < 16; ++r) {
          float s = st[r];
          float a = fmaf(s, fmaf(s, 0.03125f, 0.25f), 1.0f);
          zcA[r & 3] += a; pr[r] = a;
        }
      }

      // P -> two PV A-frags (kv 0..15 / 16..31) via cvt_pk + permlane32_swap
      union PA { short8 s; unsigned int wd[4]; } pa0, pa1;
      {
        unsigned int x0 = pkbf(pr[0], pr[1]), x1 = pkbf(pr[2], pr[3]);
        unsigned int y0 = pkbf(pr[4], pr[5]), y1 = pkbf(pr[6], pr[7]);
        plswap(x0, y0); plswap(x1, y1);
        pa0.wd[0] = x0; pa0.wd[1] = x1; pa0.wd[2] = y0; pa0.wd[3] = y1;
      }
      {
        unsigned int x0 = pkbf(pr[8], pr[9]),  x1 = pkbf(pr[10], pr[11]);
        unsigned int y0 = pkbf(pr[12], pr[13]), y1 = pkbf(pr[14], pr[15]);
        plswap(x0, y0); plswap(x1, y1);
        pa1.wd[0] = x0; pa1.wd[1] = x1; pa1.wd[2] = y0; pa1.wd[3] = y1;
      }

      // PV: B[k=kv][n=hd] frags from swizzled Vs; 8 MFMAs, 2 chained per nc
      __builtin_amdgcn_s_setprio(1);
#pragma unroll
      for (int nc = 0; nc < 4; ++nc) {
        const int hd = nc * 32 + col;
        V16 v0, v1;
        v0.v = *(const u32x4*)&Vs[cur][hd][(((kvp * 4 + hi)     ^ (hd & 7)) * 8)];
        v1.v = *(const u32x4*)&Vs[cur][hd][(((kvp * 4 + 2 + hi) ^ (hd & 7)) * 8)];
        oacc[nc] = __builtin_amdgcn_mfma_f32_32x32x16_bf16(pa0.s, v0.s, oacc[nc], 0, 0, 0);
        oacc[nc] = __builtin_amdgcn_mfma_f32_32x32x16_bf16(pa1.s, v1.s, oacc[nc], 0, 0, 0);
      }
      __builtin_amdgcn_s_setprio(0);
    }
    __syncthreads();   // drains DMA (vmcnt) + guards buffer reuse
    if (t < qt) kf = kfn;
  }

  // z: merge split chains, then lane + lane^32 (rows 4..7 offset half)
  float zcol = (zcA[0] + zcA[1]) + (zcA[2] + zcA[3]);
  zcol += __shfl_xor(zcol, 32, 64);

  // combine kv-parity partials: waves 2,3 donate through LDS (reuse Vs)
  float* fbuf = (float*)&Vs[0][0][0];        // 8192 floats = 32 KB
  if (w >= 2) {
    const int base = (w & 1) * 4096;
#pragma unroll
    for (int nc = 0; nc < 4; ++nc)
#pragma unroll
      for (int g = 0; g < 4; ++g) {
        f32x4 v = {oacc[nc][4 * g], oacc[nc][4 * g + 1],
                   oacc[nc][4 * g + 2], oacc[nc][4 * g + 3]};
        *(f32x4*)&fbuf[base + ((nc * 4 + g) * 64 + lane) * 4] = v;
      }
    if (lane < 32) zbuf[w & 1][lane] = zcol;
  }
  __syncthreads();
  if (w < 2) {
    const int base = w * 4096;
#pragma unroll
    for (int nc = 0; nc < 4; ++nc)
#pragma unroll
      for (int g = 0; g < 4; ++g) {
        f32x4 v = *(const f32x4*)&fbuf[base + ((nc * 4 + g) * 64 + lane) * 4];
#pragma unroll
        for (int r = 0; r < 4; ++r) oacc[nc][4 * g + r] += v[r];
      }
    const float zinv = 1.0f / (zcol + zbuf[w][col] + 1e-12f);
    // D[q][hd]: col = lane&31 = hd-offset, row q = (r&3)+8*(r>>2)+4*hi
#pragma unroll
    for (int g = 0; g < 4; ++g)
#pragma unroll
      for (int rr = 0; rr < 4; ++rr) {
        const int qrow = rr + 8 * g + 4 * hi;
        const float iv = __shfl(zinv, qrow, 64);
        const size_t base_o = (size_t)(b * 2048 + q0 + qrow) * 1536 + h * 128 + col;
#pragma unroll
        for (int nc = 0; nc < 4; ++nc)
          obuf[base_o + nc * 32] = f2bf(oacc[nc][4 * g + rr] * iv);
      }
  }
#undef STAGE_V
}

// ---- launch -----------------------------------------------------------
extern "C" void kernel_launch(void* const* d_in, const int* in_sizes, int n_in,
                              void* d_out, int out_size, void* d_ws, size_t ws_size,
                              hipStream_t stream) {
  const void* hs = d_in[0];
  const void* Wq = d_in[1];
  const void* Wk = d_in[2];
  const void* Wv = d_in[3];
  const void* Wo = d_in[4];
  const unsigned short* hsp = (const unsigned short*)hs;

  // ws (~39 MB): WT[1920][1536] | WoT[1536][1536] | qkvb[4096][384]
  //              | hsb[4096][1536] | vT[24*128][2048]
  unsigned short* ws   = (unsigned short*)d_ws;
  unsigned short* WT   = ws;                        // q 0..191, k 192..383, v 384..1919
  unsigned short* WoT  = WT + 1920 * 1536;
  unsigned short* qkvb = WoT + 1536 * 1536;         // compact q|k only, ld=384
  unsigned short* hsb  = qkvb + 4096 * 384;
  unsigned short* vT   = hsb + 4096 * 1536;
  unsigned short* obuf = hsb;                       // hsb dead after qkv gemm

  // weights transpose + hs convert, one dispatch
  w_tr<<<dim3(48, 64, 5), 256, 0, stream>>>(Wq, Wk, Wv, Wo, hs, WT, WoT, hsb);

  // fused q|k|v projection: qk -> qkvb (ld 384); v -> vT transposed (fused)
  gemm_bt<<<dim3(15, 32, 1), 256, 0, stream>>>(hsb, WT, qkvb, 4096, 1920, 1536,
                                               384, vT, nullptr);

  // fused causal based-attention (32x32 swapped-QK^T, kv-parity split)
  attn_based<<<dim3(24, 32, 1), 256, 0, stream>>>(qkvb, vT, obuf);

  // output projection -> d_out (fp32 store iff inputs were fp32)
  gemm_bt<<<dim3(12, 32, 1), 256, 0, stream>>>(obuf, WoT, d_out, 4096, 1536, 1536,
                                               1536, nullptr, hsp);
}

// Round 5
// 199.552 us; speedup vs baseline: 1.2009x; 1.0377x over previous
//
#include <hip/hip_runtime.h>
#include <hip/hip_bf16.h>

// ---- types ------------------------------------------------------------
typedef short short8 __attribute__((ext_vector_type(8)));   // 8 bf16 MFMA A/B frag
typedef float f32x4  __attribute__((ext_vector_type(4)));   // MFMA C/D frag (16x16)
typedef float f32x16 __attribute__((ext_vector_type(16)));  // MFMA C/D frag (32x32)
typedef unsigned int u32x4 __attribute__((ext_vector_type(4))); // 16B vehicle
typedef unsigned short u16x4 __attribute__((ext_vector_type(4))); // 8B vehicle

union V16   { u32x4 v; short8 s; };
union U16x8 { u32x4 v; unsigned short u[8]; };
union FB4   { u32x4 v; float f[4]; };
union BF2U  { __hip_bfloat162 h; unsigned int u; };

__device__ inline unsigned short f2bf(float f) {
  union { float f; unsigned int u; } x; x.f = f;
  unsigned int u = x.u + 0x7fffu + ((x.u >> 16) & 1u);   // RNE
  return (unsigned short)(u >> 16);
}

__device__ __forceinline__ unsigned int pkbf(float a, float b) {
  BF2U p; p.h = __float22bfloat162_rn(make_float2(a, b)); return p.u;
}

// v_permlane32_swap_b32: a'[0:31]=a[0:31], a'[32:63]=b[0:31],
//                        b'[0:31]=a[32:63], b'[32:63]=b[32:63]
__device__ __forceinline__ void plswap(unsigned int& a, unsigned int& b) {
  asm("v_permlane32_swap_b32 %0, %1" : "+v"(a), "+v"(b));
}

// fp32-vs-bf16 input detection from hs's first 64 even u16 words
__device__ __forceinline__ int probe_fp32(const unsigned short* hs) {
  int bad = 0;
#pragma unroll
  for (int i = 0; i < 64; ++i) {
    unsigned int e = (hs[2 * i] >> 7) & 0xFFu;
    if (e >= 0xFEu || (e > 0u && e < 0x60u)) bad++;
  }
  return bad >= 6;
}

// async global->LDS DMA, 16B/lane; LDS dest = wave-uniform base + lane*16
__device__ __forceinline__ void gl_lds16(const unsigned short* g, unsigned short* l) {
  __builtin_amdgcn_global_load_lds(
      (const __attribute__((address_space(1))) unsigned int*)g,
      (__attribute__((address_space(3))) unsigned int*)l, 16, 0, 0);
}

// ---- weights transpose (z=0..3) + hs convert (z=4), one dispatch ------
// Round-14: 64x64 transpose tiles, 16B/lane global loads AND stores (the
// old 32x32 scalar-store version ran at 13.7% HBM, 42 us — 4x off its
// roofline). LDS tile [64][72] shorts with r-block XOR swizzle
// (r ^ (((c>>1)&7)<<3)) — read side stays one aligned ds_read_b128.
// z=0: Wq->WT[0:192), z=1: Wk->WT[192:384), z=2: Wv->WT[384:1920), z=3: Wo->WoT
// z=4: hs -> hsb (bf16 contiguous), block idx = y*24+x, 2048 el/block
// grid (24, 128, 5): z=4 uses all 3072 blocks; transposes early-exit.
__global__ __launch_bounds__(256) void w_tr(const void* __restrict__ Wq,
                                            const void* __restrict__ Wk,
                                            const void* __restrict__ Wv,
                                            const void* __restrict__ Wo,
                                            const void* __restrict__ hs,
                                            unsigned short* __restrict__ WT,
                                            unsigned short* __restrict__ WoT,
                                            unsigned short* __restrict__ hsb) {
  __shared__ unsigned short t[64 * 72];    // 9 KB
  __shared__ int sf;
  const int z = blockIdx.z;
  if (z == 4) {                            // hs convert path
    if (threadIdx.x == 0) sf = probe_fp32((const unsigned short*)hs);
    __syncthreads();
    const int f = sf;
    size_t i0 = ((size_t)(blockIdx.y * 24 + blockIdx.x) * 256 + threadIdx.x) * 8;
    if (f) {
      const float* in = (const float*)hs;
      FB4 a, b; a.v = *(const u32x4*)&in[i0]; b.v = *(const u32x4*)&in[i0 + 4];
      U16x8 p;
#pragma unroll
      for (int j = 0; j < 4; ++j) { p.u[j] = f2bf(a.f[j]); p.u[j + 4] = f2bf(b.f[j]); }
      *(u32x4*)&hsb[i0] = p.v;
    } else {
      *(u32x4*)&hsb[i0] = *(const u32x4*)((const unsigned short*)hs + i0);
    }
    return;
  }
  if (blockIdx.y >= 24) return;            // transpose: 24 row-tiles of 64
  const void* in_; unsigned short* out; int C;
  if      (z == 0) { in_ = Wq; out = WT;              C = 192;  }
  else if (z == 1) { in_ = Wk; out = WT + 192 * 1536; C = 192;  }
  else if (z == 2) { in_ = Wv; out = WT + 384 * 1536; C = 1536; }
  else             { in_ = Wo; out = WoT;             C = 1536; }
  const int c0 = blockIdx.x * 64;
  if (c0 >= C) return;                     // uniform early exit
  if (threadIdx.x == 0) sf = probe_fp32((const unsigned short*)hs);
  __syncthreads();
  const int f = sf;
  const int r0 = blockIdx.y * 64;          // R = 1536 rows for all four
  const int tx = threadIdx.x & 15;         // 4-col group
  const int ty = threadIdx.x >> 4;         // row-in-16
  // load 64x64 (4 rounds of 16 rows), convert, swizzled LDS scatter
#pragma unroll
  for (int j = 0; j < 4; ++j) {
    const int r = ty + 16 * j;
    const size_t idx = (size_t)(r0 + r) * C + c0 + tx * 4;
    float v[4];
    if (f) {
      FB4 a; a.v = *(const u32x4*)&((const float*)in_)[idx];
#pragma unroll
      for (int i = 0; i < 4; ++i) {
        const int c = tx * 4 + i;
        t[c * 72 + (r ^ (((c >> 1) & 7) << 3))] = f2bf(a.f[i]);
      }
    } else {
      u16x4 a = *(const u16x4*)&((const unsigned short*)in_)[idx];
#pragma unroll
      for (int i = 0; i < 4; ++i) {
        const int c = tx * 4 + i;
        t[c * 72 + (r ^ (((c >> 1) & 7) << 3))] = a[i];
      }
    }
  }
  __syncthreads();
  // store transposed: 2 rounds, 16B/lane, 128B contiguous per 8 lanes
#pragma unroll
  for (int jj = 0; jj < 2; ++jj) {
    const int c = (threadIdx.x >> 3) + 32 * jj;
    const int rb = (threadIdx.x & 7) * 8;
    const int rsw = rb ^ (((c >> 1) & 7) << 3);
    u32x4 v = *(const u32x4*)&t[c * 72 + rsw];
    *(u32x4*)&out[(size_t)(c0 + c) * 1536 + r0 + rb] = v;
  }
}

// ---- C = A[M][K] @ BT[NB][K]^T, bf16 — proven 2-phase + fused v-transpose
// 2-phase structure from round-10/11. For the qkv call, v-column blocks
// (n0>=384) write their C-tile TRANSPOSED into vT[(b*12+h)*128+hd][l] via
// an LDS round-trip in the epilogue (staging buffers dead there) —
// eliminates the tr_v dispatch. qk columns land compact, ldC=384.
__global__ __launch_bounds__(256) void gemm_bt(const unsigned short* __restrict__ A,
                                               const unsigned short* __restrict__ BT,
                                               void* __restrict__ C_,
                                               int M, int NB, int K, int ldC,
                                               unsigned short* __restrict__ vTout,
                                               const unsigned short* __restrict__ probe_src) {
  __shared__ unsigned short smem[4 * 128 * 64];      // As[2]|Bs[2], 64 KB
#define AS(buf, r, c) smem[(((buf) * 128) + (r)) * 64 + (c)]
#define BS(buf, r, c) smem[(((2 + (buf)) * 128) + (r)) * 64 + (c)]
  const int m0 = blockIdx.y * 128, n0 = blockIdx.x * 128;
  const int tid = threadIdx.x;
  const int lane = tid & 63, w = tid >> 6;
  const int wr = w >> 1, wc = w & 1;
  const int quad = lane >> 4, mrow = lane & 15;

  const int sr = lane >> 3;                          // staging row-in-8
  const int sc = ((lane & 7) ^ (lane >> 3)) * 8;     // swizzled global chunk (shorts)
  const int fsw = (mrow & 7);                        // frag-read swizzle

  const f32x4 zf = {0.f, 0.f, 0.f, 0.f};
  f32x4 acc[4][4];
#pragma unroll
  for (int mt = 0; mt < 4; ++mt)
#pragma unroll
    for (int nt = 0; nt < 4; ++nt) acc[mt][nt] = zf;

  const int nk = K >> 6;                             // BK=64 steps
  // prologue: stage tile 0 into buffer 0 (4 A-loads + 4 B-loads per wave)
#pragma unroll
  for (int j = 0; j < 4; ++j) {
    const int r = 32 * w + 8 * j + sr;
    gl_lds16(&A [(size_t)(m0 + r) * K + sc], &AS(0, 32 * w + 8 * j, 0));
    gl_lds16(&BT[(size_t)(n0 + r) * K + sc], &BS(0, 32 * w + 8 * j, 0));
  }

  for (int ks = 0; ks < nk; ++ks) {
    const int cur = ks & 1;
    __syncthreads();   // drains DMA for buf[cur]; prior reads of buf[cur^1] done
    if (ks + 1 < nk) {
      const int k1 = (ks + 1) << 6;
#pragma unroll
      for (int j = 0; j < 4; ++j) {
        const int r = 32 * w + 8 * j + sr;
        gl_lds16(&A [(size_t)(m0 + r) * K + k1 + sc], &AS(cur ^ 1, 32 * w + 8 * j, 0));
        gl_lds16(&BT[(size_t)(n0 + r) * K + k1 + sc], &BS(cur ^ 1, 32 * w + 8 * j, 0));
      }
    }
#pragma unroll
    for (int kq = 0; kq < 2; ++kq) {
      short8 afr[4], bfr[4];
#pragma unroll
      for (int mt = 0; mt < 4; ++mt) {
        V16 u; u.v = *(const u32x4*)&AS(cur, wr * 64 + mt * 16 + mrow, ((kq * 4 + quad) ^ fsw) * 8);
        afr[mt] = u.s;
      }
#pragma unroll
      for (int nt = 0; nt < 4; ++nt) {
        V16 u; u.v = *(const u32x4*)&BS(cur, wc * 64 + nt * 16 + mrow, ((kq * 4 + quad) ^ fsw) * 8);
        bfr[nt] = u.s;
      }
#pragma unroll
      for (int mt = 0; mt < 4; ++mt)
#pragma unroll
        for (int nt = 0; nt < 4; ++nt)
          acc[mt][nt] = __builtin_amdgcn_mfma_f32_16x16x32_bf16(afr[mt], bfr[nt], acc[mt][nt], 0, 0, 0);
    }
  }

  __syncthreads();                                   // staging LDS now reusable
  if (vTout != nullptr && n0 >= 384) {
    // v-columns: transpose 64x64 wave tile through LDS, store [hd][l]
    unsigned short* T = smem + w * (64 * 72);        // pad 72: 16B-aligned rows
#pragma unroll
    for (int mt = 0; mt < 4; ++mt)
#pragma unroll
      for (int nt = 0; nt < 4; ++nt)
#pragma unroll
        for (int r = 0; r < 4; ++r)
          T[(nt * 16 + mrow) * 72 + mt * 16 + quad * 4 + r] = f2bf(acc[mt][nt][r]);
    asm volatile("s_waitcnt lgkmcnt(0)" ::: "memory");
    const int h  = (n0 - 384) >> 7;                  // head (block-uniform)
    const int gb = (m0 + wr * 64) >> 11;             // batch
    const int l0 = (m0 + wr * 64) & 2047;            // seq offset
    const size_t vrow0 = ((size_t)(gb * 12 + h) << 7) + wc * 64;
#pragma unroll
    for (int i = 0; i < 8; ++i) {
      const int row = (lane >> 3) + 8 * i;           // hd_local 0..63
      const int ch  = (lane & 7) * 8;                // l chunk
      u32x4 vv = *(const u32x4*)&T[row * 72 + ch];
      *(u32x4*)&vTout[(vrow0 + row) * 2048 + l0 + ch] = vv;
    }
  } else {
    const int of = probe_src ? probe_fp32(probe_src) : 0;
#pragma unroll
    for (int mt = 0; mt < 4; ++mt)
#pragma unroll
      for (int nt = 0; nt < 4; ++nt)
#pragma unroll
        for (int r = 0; r < 4; ++r) {
          int grow = m0 + wr * 64 + mt * 16 + quad * 4 + r;
          int gcol = n0 + wc * 64 + nt * 16 + mrow;
          size_t idx = (size_t)grow * ldC + gcol;
          if (of) ((float*)C_)[idx] = acc[mt][nt][r];
          else    ((unsigned short*)C_)[idx] = f2bf(acc[mt][nt][r]);
        }
  }
#undef AS
#undef BS
}

// ---- fused causal "based" attention — 32x32 swapped-QK^T ---------------
// qkv: [4096][384] bf16 (cols 0..191 q, 192..383 k); vT: [24*128][2048]
// obuf: [4096][1536]. grid (24,32): (b*12+h, q-tile of 64). 256 threads.
__global__ __launch_bounds__(256, 3) void attn_based(const unsigned short* __restrict__ qkv,
                                                     const unsigned short* __restrict__ vT,
                                                     unsigned short* __restrict__ obuf) {
  __shared__ unsigned short Vs[2][128][64];  // [buf][hd][kv] bf16, 32 KB (DMA dest)
  __shared__ float zbuf[2][32];
  const int LD = 384;
  const int bh = blockIdx.x;
  const int qt = 31 - blockIdx.y;            // long blocks dispatch first (LPT)
  const int b = bh / 12, h = bh % 12;
  const int tid = threadIdx.x;
  const int lane = tid & 63, w = tid >> 6;
  const int qsub = w & 1, kvp = w >> 1;      // q-subtile / kv-parity of this wave
  const int col = lane & 31, hi = lane >> 5;

  const int q0 = qt * 64 + qsub * 32;        // wave's q block start (abs)
  const int q_abs = q0 + col;

  // Q B-frag (loop-invariant): B[k=f][n=q]: lane holds q=col, f=hi*8+j
  V16 bq; bq.v = *(const u32x4*)&qkv[(size_t)(b * 2048 + q_abs) * LD + h * 16 + hi * 8];

  // K A-frag: A[m=kv][k=f]: lane holds kv=col (+kv0), f=hi*8+j
  const unsigned short* kptr =
      &qkv[(size_t)(b * 2048 + kvp * 32 + col) * LD + 192 + h * 16 + hi * 8];

  const unsigned short* vbase = vT + (size_t)(bh * 128) * 2048;

  const f32x16 z16 = {0.f,0.f,0.f,0.f,0.f,0.f,0.f,0.f,0.f,0.f,0.f,0.f,0.f,0.f,0.f,0.f};
  f32x16 oacc[4];                            // [hd-chunk of 32]
#pragma unroll
  for (int nc = 0; nc < 4; ++nc) oacc[nc] = z16;
  float zcA[4] = {0.f, 0.f, 0.f, 0.f};       // split z chains (merged at end)

#define STAGE_V(KV0, BUF)                                                     \
  {                                                                           \
    _Pragma("unroll")                                                         \
    for (int j = 0; j < 4; ++j) {                                             \
      const int row = 32 * w + 8 * j + (lane >> 3);                           \
      gl_lds16(vbase + (size_t)row * 2048 + (KV0) + ((lane & 7) ^ (lane >> 3)) * 8, \
               &Vs[BUF][32 * w + 8 * j][0]);                                  \
    }                                                                         \
  }

  STAGE_V(0, 0);
  V16 kf; kf.v = *(const u32x4*)kptr;        // K frag for tile 0
  __syncthreads();

  for (int t = 0; t <= qt; ++t) {
    const int cur = t & 1;
    if (t < qt) STAGE_V((t + 1) * 64, cur ^ 1);

    V16 kfn;
    kptr += (size_t)64 * LD;
    if (t < qt) kfn.v = *(const u32x4*)kptr;   // prefetch next K frag

    // wave-uniform: does this wave's kv sub-block exist under the causal mask?
    const bool live = (t < qt) | (kvp <= qsub);
    if (live) {
      // S^T[kv][q] in one MFMA: col = lane&31 = q, row kv = (r&3)+8*(r>>2)+4*hi
      f32x16 st = __builtin_amdgcn_mfma_f32_32x32x16_bf16(kf.s, bq.s, z16, 0, 0, 0);
      const int kv0 = t * 64 + kvp * 32;
      const bool diag = (t == qt) & (kvp == qsub);
      float pr[16];
      if (diag) {
#pragma unroll
        for (int r = 0; r < 16; ++r) {
          float s = st[r];
          float a = fmaf(s, fmaf(s, 0.03125f, 0.25f), 1.0f);
          const int kvr = kv0 + (r & 3) + 8 * (r >> 2) + 4 * hi;
          a = (kvr <= q_abs) ? a : 0.0f;
          zcA[r & 3] += a; pr[r] = a;
        }
      } else {
#pragma unroll
        for (int r = 0; r < 16; ++r) {
          float s = st[r];
          float a = fmaf(s, fmaf(s, 0.03125f, 0.25f), 1.0f);
          zcA[r & 3] += a; pr[r] = a;
        }
      }

      // P -> two PV A-frags (kv 0..15 / 16..31) via cvt_pk + permlane32_swap
      union PA { short8 s; unsigned int wd[4]; } pa0, pa1;
      {
        unsigned int x0 = pkbf(pr[0], pr[1]), x1 = pkbf(pr[2], pr[3]);
        unsigned int y0 = pkbf(pr[4], pr[5]), y1 = pkbf(pr[6], pr[7]);
        plswap(x0, y0); plswap(x1, y1);
        pa0.wd[0] = x0; pa0.wd[1] = x1; pa0.wd[2] = y0; pa0.wd[3] = y1;
      }
      {
        unsigned int x0 = pkbf(pr[8], pr[9]),  x1 = pkbf(pr[10], pr[11]);
        unsigned int y0 = pkbf(pr[12], pr[13]), y1 = pkbf(pr[14], pr[15]);
        plswap(x0, y0); plswap(x1, y1);
        pa1.wd[0] = x0; pa1.wd[1] = x1; pa1.wd[2] = y0; pa1.wd[3] = y1;
      }

      // PV: B[k=kv][n=hd] frags from swizzled Vs; 8 MFMAs, 2 chained per nc
      __builtin_amdgcn_s_setprio(1);
#pragma unroll
      for (int nc = 0; nc < 4; ++nc) {
        const int hd = nc * 32 + col;
        V16 v0, v1;
        v0.v = *(const u32x4*)&Vs[cur][hd][(((kvp * 4 + hi)     ^ (hd & 7)) * 8)];
        v1.v = *(const u32x4*)&Vs[cur][hd][(((kvp * 4 + 2 + hi) ^ (hd & 7)) * 8)];
        oacc[nc] = __builtin_amdgcn_mfma_f32_32x32x16_bf16(pa0.s, v0.s, oacc[nc], 0, 0, 0);
        oacc[nc] = __builtin_amdgcn_mfma_f32_32x32x16_bf16(pa1.s, v1.s, oacc[nc], 0, 0, 0);
      }
      __builtin_amdgcn_s_setprio(0);
    }
    __syncthreads();   // drains DMA (vmcnt) + guards buffer reuse
    if (t < qt) kf = kfn;
  }

  // z: merge split chains, then lane + lane^32 (rows 4..7 offset half)
  float zcol = (zcA[0] + zcA[1]) + (zcA[2] + zcA[3]);
  zcol += __shfl_xor(zcol, 32, 64);

  // combine kv-parity partials: waves 2,3 donate through LDS (reuse Vs)
  float* fbuf = (float*)&Vs[0][0][0];        // 8192 floats = 32 KB
  if (w >= 2) {
    const int base = (w & 1) * 4096;
#pragma unroll
    for (int nc = 0; nc < 4; ++nc)
#pragma unroll
      for (int g = 0; g < 4; ++g) {
        f32x4 v = {oacc[nc][4 * g], oacc[nc][4 * g + 1],
                   oacc[nc][4 * g + 2], oacc[nc][4 * g + 3]};
        *(f32x4*)&fbuf[base + ((nc * 4 + g) * 64 + lane) * 4] = v;
      }
    if (lane < 32) zbuf[w & 1][lane] = zcol;
  }
  __syncthreads();
  if (w < 2) {
    const int base = w * 4096;
#pragma unroll
    for (int nc = 0; nc < 4; ++nc)
#pragma unroll
      for (int g = 0; g < 4; ++g) {
        f32x4 v = *(const f32x4*)&fbuf[base + ((nc * 4 + g) * 64 + lane) * 4];
#pragma unroll
        for (int r = 0; r < 4; ++r) oacc[nc][4 * g + r] += v[r];
      }
    const float zinv = 1.0f / (zcol + zbuf[w][col] + 1e-12f);
    // D[q][hd]: col = lane&31 = hd-offset, row q = (r&3)+8*(r>>2)+4*hi
#pragma unroll
    for (int g = 0; g < 4; ++g)
#pragma unroll
      for (int rr = 0; rr < 4; ++rr) {
        const int qrow = rr + 8 * g + 4 * hi;
        const float iv = __shfl(zinv, qrow, 64);
        const size_t base_o = (size_t)(b * 2048 + q0 + qrow) * 1536 + h * 128 + col;
#pragma unroll
        for (int nc = 0; nc < 4; ++nc)
          obuf[base_o + nc * 32] = f2bf(oacc[nc][4 * g + rr] * iv);
      }
  }
#undef STAGE_V
}

// ---- launch -----------------------------------------------------------
extern "C" void kernel_launch(void* const* d_in, const int* in_sizes, int n_in,
                              void* d_out, int out_size, void* d_ws, size_t ws_size,
                              hipStream_t stream) {
  const void* hs = d_in[0];
  const void* Wq = d_in[1];
  const void* Wk = d_in[2];
  const void* Wv = d_in[3];
  const void* Wo = d_in[4];
  const unsigned short* hsp = (const unsigned short*)hs;

  // ws (~39 MB): WT[1920][1536] | WoT[1536][1536] | qkvb[4096][384]
  //              | hsb[4096][1536] | vT[24*128][2048]
  unsigned short* ws   = (unsigned short*)d_ws;
  unsigned short* WT   = ws;                        // q 0..191, k 192..383, v 384..1919
  unsigned short* WoT  = WT + 1920 * 1536;
  unsigned short* qkvb = WoT + 1536 * 1536;         // compact q|k only, ld=384
  unsigned short* hsb  = qkvb + 4096 * 384;
  unsigned short* vT   = hsb + 4096 * 1536;
  unsigned short* obuf = hsb;                       // hsb dead after qkv gemm

  // weights transpose + hs convert, one dispatch
  w_tr<<<dim3(24, 128, 5), 256, 0, stream>>>(Wq, Wk, Wv, Wo, hs, WT, WoT, hsb);

  // fused q|k|v projection: qk -> qkvb (ld 384); v -> vT transposed (fused)
  gemm_bt<<<dim3(15, 32, 1), 256, 0, stream>>>(hsb, WT, qkvb, 4096, 1920, 1536,
                                               384, vT, nullptr);

  // fused causal based-attention (32x32 swapped-QK^T, kv-parity split)
  attn_based<<<dim3(24, 32, 1), 256, 0, stream>>>(qkvb, vT, obuf);

  // output projection -> d_out (fp32 store iff inputs were fp32)
  gemm_bt<<<dim3(12, 32, 1), 256, 0, stream>>>(obuf, WoT, d_out, 4096, 1536, 1536,
                                               1536, nullptr, hsp);
}

// Round 6
// 193.682 us; speedup vs baseline: 1.2373x; 1.0303x over previous
//
#include <hip/hip_runtime.h>
#include <hip/hip_bf16.h>

// ---- types ------------------------------------------------------------
typedef short short8 __attribute__((ext_vector_type(8)));   // 8 bf16 MFMA A/B frag
typedef float f32x4  __attribute__((ext_vector_type(4)));   // MFMA C/D frag (16x16)
typedef float f32x16 __attribute__((ext_vector_type(16)));  // MFMA C/D frag (32x32)
typedef unsigned int u32x4 __attribute__((ext_vector_type(4))); // 16B vehicle
typedef unsigned short u16x4 __attribute__((ext_vector_type(4))); // 8B vehicle

union V16   { u32x4 v; short8 s; };
union U16x8 { u32x4 v; unsigned short u[8]; };
union FB4   { u32x4 v; float f[4]; };
union BF2U  { __hip_bfloat162 h; unsigned int u; };

__device__ inline unsigned short f2bf(float f) {
  union { float f; unsigned int u; } x; x.f = f;
  unsigned int u = x.u + 0x7fffu + ((x.u >> 16) & 1u);   // RNE
  return (unsigned short)(u >> 16);
}

__device__ __forceinline__ unsigned int pkbf(float a, float b) {
  BF2U p; p.h = __float22bfloat162_rn(make_float2(a, b)); return p.u;
}

// v_permlane32_swap_b32: a'[0:31]=a[0:31], a'[32:63]=b[0:31],
//                        b'[0:31]=a[32:63], b'[32:63]=b[32:63]
__device__ __forceinline__ void plswap(unsigned int& a, unsigned int& b) {
  asm("v_permlane32_swap_b32 %0, %1" : "+v"(a), "+v"(b));
}

// fp32-vs-bf16 input detection from hs's first 64 even u16 words
__device__ __forceinline__ int probe_fp32(const unsigned short* hs) {
  int bad = 0;
#pragma unroll
  for (int i = 0; i < 64; ++i) {
    unsigned int e = (hs[2 * i] >> 7) & 0xFFu;
    if (e >= 0xFEu || (e > 0u && e < 0x60u)) bad++;
  }
  return bad >= 6;
}

// async global->LDS DMA, 16B/lane; LDS dest = wave-uniform base + lane*16
__device__ __forceinline__ void gl_lds16(const unsigned short* g, unsigned short* l) {
  __builtin_amdgcn_global_load_lds(
      (const __attribute__((address_space(1))) unsigned int*)g,
      (__attribute__((address_space(3))) unsigned int*)l, 16, 0, 0);
}

#define PIN() __builtin_amdgcn_sched_barrier(0)

// ---- weights transpose (z=0..3) + hs convert (z=4), one dispatch ------
// 64x64 transpose tiles, 16B/lane global loads AND stores. LDS tile
// [64][72] shorts with r-block XOR swizzle (r ^ (((c>>1)&7)<<3)).
// z=0: Wq->WT[0:192), z=1: Wk->WT[192:384), z=2: Wv->WT[384:1920), z=3: Wo->WoT
// z=4: hs -> hsb (bf16 contiguous), block idx = y*24+x, 2048 el/block
__global__ __launch_bounds__(256) void w_tr(const void* __restrict__ Wq,
                                            const void* __restrict__ Wk,
                                            const void* __restrict__ Wv,
                                            const void* __restrict__ Wo,
                                            const void* __restrict__ hs,
                                            unsigned short* __restrict__ WT,
                                            unsigned short* __restrict__ WoT,
                                            unsigned short* __restrict__ hsb) {
  __shared__ unsigned short t[64 * 72];    // 9 KB
  __shared__ int sf;
  const int z = blockIdx.z;
  if (z == 4) {                            // hs convert path
    if (threadIdx.x == 0) sf = probe_fp32((const unsigned short*)hs);
    __syncthreads();
    const int f = sf;
    size_t i0 = ((size_t)(blockIdx.y * 24 + blockIdx.x) * 256 + threadIdx.x) * 8;
    if (f) {
      const float* in = (const float*)hs;
      FB4 a, b; a.v = *(const u32x4*)&in[i0]; b.v = *(const u32x4*)&in[i0 + 4];
      U16x8 p;
#pragma unroll
      for (int j = 0; j < 4; ++j) { p.u[j] = f2bf(a.f[j]); p.u[j + 4] = f2bf(b.f[j]); }
      *(u32x4*)&hsb[i0] = p.v;
    } else {
      *(u32x4*)&hsb[i0] = *(const u32x4*)((const unsigned short*)hs + i0);
    }
    return;
  }
  if (blockIdx.y >= 24) return;            // transpose: 24 row-tiles of 64
  const void* in_; unsigned short* out; int C;
  if      (z == 0) { in_ = Wq; out = WT;              C = 192;  }
  else if (z == 1) { in_ = Wk; out = WT + 192 * 1536; C = 192;  }
  else if (z == 2) { in_ = Wv; out = WT + 384 * 1536; C = 1536; }
  else             { in_ = Wo; out = WoT;             C = 1536; }
  const int c0 = blockIdx.x * 64;
  if (c0 >= C) return;                     // uniform early exit
  if (threadIdx.x == 0) sf = probe_fp32((const unsigned short*)hs);
  __syncthreads();
  const int f = sf;
  const int r0 = blockIdx.y * 64;          // R = 1536 rows for all four
  const int tx = threadIdx.x & 15;         // 4-col group
  const int ty = threadIdx.x >> 4;         // row-in-16
  // load 64x64 (4 rounds of 16 rows), convert, swizzled LDS scatter
#pragma unroll
  for (int j = 0; j < 4; ++j) {
    const int r = ty + 16 * j;
    const size_t idx = (size_t)(r0 + r) * C + c0 + tx * 4;
    if (f) {
      FB4 a; a.v = *(const u32x4*)&((const float*)in_)[idx];
#pragma unroll
      for (int i = 0; i < 4; ++i) {
        const int c = tx * 4 + i;
        t[c * 72 + (r ^ (((c >> 1) & 7) << 3))] = f2bf(a.f[i]);
      }
    } else {
      u16x4 a = *(const u16x4*)&((const unsigned short*)in_)[idx];
#pragma unroll
      for (int i = 0; i < 4; ++i) {
        const int c = tx * 4 + i;
        t[c * 72 + (r ^ (((c >> 1) & 7) << 3))] = a[i];
      }
    }
  }
  __syncthreads();
  // store transposed: 2 rounds, 16B/lane, 128B contiguous per 8 lanes
#pragma unroll
  for (int jj = 0; jj < 2; ++jj) {
    const int c = (threadIdx.x >> 3) + 32 * jj;
    const int rb = (threadIdx.x & 7) * 8;
    const int rsw = rb ^ (((c >> 1) & 7) << 3);
    u32x4 v = *(const u32x4*)&t[c * 72 + rsw];
    *(u32x4*)&out[(size_t)(c0 + c) * 1536 + r0 + rb] = v;
  }
}

// ---- C = A[M][K] @ BT[NB][K]^T, bf16 — proven 2-phase + fused v-transpose
// Round-15: + bijective XCD-aware block swizzle (T1): consecutive wgids
// (same m-panel) land on one XCD's L2 -> A-panel reuse stays local.
// Grids are 480/384 blocks, both % 8 == 0.
__global__ __launch_bounds__(256) void gemm_bt(const unsigned short* __restrict__ A,
                                               const unsigned short* __restrict__ BT,
                                               void* __restrict__ C_,
                                               int M, int NB, int K, int ldC,
                                               unsigned short* __restrict__ vTout,
                                               const unsigned short* __restrict__ probe_src) {
  __shared__ unsigned short smem[4 * 128 * 64];      // As[2]|Bs[2], 64 KB
#define AS(buf, r, c) smem[(((buf) * 128) + (r)) * 64 + (c)]
#define BS(buf, r, c) smem[(((2 + (buf)) * 128) + (r)) * 64 + (c)]
  // XCD swizzle: orig dispatch order (x-fastest) -> contiguous chunk per XCD
  const int gx = gridDim.x;
  const int nwg = gx * gridDim.y;
  const int orig = blockIdx.y * gx + blockIdx.x;
  const int q8 = nwg >> 3, r8 = nwg & 7;
  const int xcd = orig & 7, inner = orig >> 3;
  const int wg = (xcd < r8 ? xcd * (q8 + 1) : r8 * (q8 + 1) + (xcd - r8) * q8) + inner;
  const int m0 = (wg / gx) * 128, n0 = (wg % gx) * 128;
  const int tid = threadIdx.x;
  const int lane = tid & 63, w = tid >> 6;
  const int wr = w >> 1, wc = w & 1;
  const int quad = lane >> 4, mrow = lane & 15;

  const int sr = lane >> 3;                          // staging row-in-8
  const int sc = ((lane & 7) ^ (lane >> 3)) * 8;     // swizzled global chunk (shorts)
  const int fsw = (mrow & 7);                        // frag-read swizzle

  const f32x4 zf = {0.f, 0.f, 0.f, 0.f};
  f32x4 acc[4][4];
#pragma unroll
  for (int mt = 0; mt < 4; ++mt)
#pragma unroll
    for (int nt = 0; nt < 4; ++nt) acc[mt][nt] = zf;

  const int nk = K >> 6;                             // BK=64 steps
  // prologue: stage tile 0 into buffer 0 (4 A-loads + 4 B-loads per wave)
#pragma unroll
  for (int j = 0; j < 4; ++j) {
    const int r = 32 * w + 8 * j + sr;
    gl_lds16(&A [(size_t)(m0 + r) * K + sc], &AS(0, 32 * w + 8 * j, 0));
    gl_lds16(&BT[(size_t)(n0 + r) * K + sc], &BS(0, 32 * w + 8 * j, 0));
  }

  for (int ks = 0; ks < nk; ++ks) {
    const int cur = ks & 1;
    __syncthreads();   // drains DMA for buf[cur]; prior reads of buf[cur^1] done
    if (ks + 1 < nk) {
      const int k1 = (ks + 1) << 6;
#pragma unroll
      for (int j = 0; j < 4; ++j) {
        const int r = 32 * w + 8 * j + sr;
        gl_lds16(&A [(size_t)(m0 + r) * K + k1 + sc], &AS(cur ^ 1, 32 * w + 8 * j, 0));
        gl_lds16(&BT[(size_t)(n0 + r) * K + k1 + sc], &BS(cur ^ 1, 32 * w + 8 * j, 0));
      }
    }
#pragma unroll
    for (int kq = 0; kq < 2; ++kq) {
      short8 afr[4], bfr[4];
#pragma unroll
      for (int mt = 0; mt < 4; ++mt) {
        V16 u; u.v = *(const u32x4*)&AS(cur, wr * 64 + mt * 16 + mrow, ((kq * 4 + quad) ^ fsw) * 8);
        afr[mt] = u.s;
      }
#pragma unroll
      for (int nt = 0; nt < 4; ++nt) {
        V16 u; u.v = *(const u32x4*)&BS(cur, wc * 64 + nt * 16 + mrow, ((kq * 4 + quad) ^ fsw) * 8);
        bfr[nt] = u.s;
      }
#pragma unroll
      for (int mt = 0; mt < 4; ++mt)
#pragma unroll
        for (int nt = 0; nt < 4; ++nt)
          acc[mt][nt] = __builtin_amdgcn_mfma_f32_16x16x32_bf16(afr[mt], bfr[nt], acc[mt][nt], 0, 0, 0);
    }
  }

  __syncthreads();                                   // staging LDS now reusable
  if (vTout != nullptr && n0 >= 384) {
    // v-columns: transpose 64x64 wave tile through LDS, store [hd][l]
    unsigned short* T = smem + w * (64 * 72);        // pad 72: 16B-aligned rows
#pragma unroll
    for (int mt = 0; mt < 4; ++mt)
#pragma unroll
      for (int nt = 0; nt < 4; ++nt)
#pragma unroll
        for (int r = 0; r < 4; ++r)
          T[(nt * 16 + mrow) * 72 + mt * 16 + quad * 4 + r] = f2bf(acc[mt][nt][r]);
    asm volatile("s_waitcnt lgkmcnt(0)" ::: "memory");
    const int h  = (n0 - 384) >> 7;                  // head (block-uniform)
    const int gb = (m0 + wr * 64) >> 11;             // batch
    const int l0 = (m0 + wr * 64) & 2047;            // seq offset
    const size_t vrow0 = ((size_t)(gb * 12 + h) << 7) + wc * 64;
#pragma unroll
    for (int i = 0; i < 8; ++i) {
      const int row = (lane >> 3) + 8 * i;           // hd_local 0..63
      const int ch  = (lane & 7) * 8;                // l chunk
      u32x4 vv = *(const u32x4*)&T[row * 72 + ch];
      *(u32x4*)&vTout[(vrow0 + row) * 2048 + l0 + ch] = vv;
    }
  } else {
    const int of = probe_src ? probe_fp32(probe_src) : 0;
#pragma unroll
    for (int mt = 0; mt < 4; ++mt)
#pragma unroll
      for (int nt = 0; nt < 4; ++nt)
#pragma unroll
        for (int r = 0; r < 4; ++r) {
          int grow = m0 + wr * 64 + mt * 16 + quad * 4 + r;
          int gcol = n0 + wc * 64 + nt * 16 + mrow;
          size_t idx = (size_t)grow * ldC + gcol;
          if (of) ((float*)C_)[idx] = acc[mt][nt][r];
          else    ((unsigned short*)C_)[idx] = f2bf(acc[mt][nt][r]);
        }
  }
#undef AS
#undef BS
}

// ---- fused causal "based" attention — 32x32 swapped-QK^T ---------------
// Round-15: ring-3 V staging with COUNTED vmcnt across raw s_barrier (T4).
// Old loop ended in __syncthreads() == s_waitcnt vmcnt(0): every kv-tile
// drained all 16 V-DMA loads (latency-bound at ~1.4 blocks/CU). Now tile
// t+2 stages while t computes; end-of-tile waits vmcnt(4) (only t+2's own
// 4 loads/wave stay in flight), so t+1's data is guaranteed without a
// full drain. K-frag prefetch pinned BEFORE the stage so vmcnt(4) covers it.
// qkv: [4096][384] bf16 (cols 0..191 q, 192..383 k); vT: [24*128][2048]
// obuf: [4096][1536]. grid (24,32): (b*12+h, q-tile of 64). 256 threads.
__global__ __launch_bounds__(256, 3) void attn_based(const unsigned short* __restrict__ qkv,
                                                     const unsigned short* __restrict__ vT,
                                                     unsigned short* __restrict__ obuf) {
  __shared__ unsigned short Vs[3][128][64];  // [ring][hd][kv] bf16, 48 KB (DMA dest)
  __shared__ float zbuf[2][32];
  const int LD = 384;
  const int bh = blockIdx.x;
  const int qt = 31 - blockIdx.y;            // long blocks dispatch first (LPT)
  const int b = bh / 12, h = bh % 12;
  const int tid = threadIdx.x;
  const int lane = tid & 63, w = tid >> 6;
  const int qsub = w & 1, kvp = w >> 1;      // q-subtile / kv-parity of this wave
  const int col = lane & 31, hi = lane >> 5;

  const int q0 = qt * 64 + qsub * 32;        // wave's q block start (abs)
  const int q_abs = q0 + col;

  // Q B-frag (loop-invariant): B[k=f][n=q]: lane holds q=col, f=hi*8+j
  V16 bq; bq.v = *(const u32x4*)&qkv[(size_t)(b * 2048 + q_abs) * LD + h * 16 + hi * 8];

  // K A-frag: A[m=kv][k=f]: lane holds kv=col (+kv0), f=hi*8+j
  const unsigned short* kptr =
      &qkv[(size_t)(b * 2048 + kvp * 32 + col) * LD + 192 + h * 16 + hi * 8];

  const unsigned short* vbase = vT + (size_t)(bh * 128) * 2048;

  const f32x16 z16 = {0.f,0.f,0.f,0.f,0.f,0.f,0.f,0.f,0.f,0.f,0.f,0.f,0.f,0.f,0.f,0.f};
  f32x16 oacc[4];                            // [hd-chunk of 32]
#pragma unroll
  for (int nc = 0; nc < 4; ++nc) oacc[nc] = z16;
  float zcA[4] = {0.f, 0.f, 0.f, 0.f};       // split z chains (merged at end)

#define STAGE_V(KV0, BUF)                                                     \
  {                                                                           \
    _Pragma("unroll")                                                         \
    for (int j = 0; j < 4; ++j) {                                             \
      const int row = 32 * w + 8 * j + (lane >> 3);                           \
      gl_lds16(vbase + (size_t)row * 2048 + (KV0) + ((lane & 7) ^ (lane >> 3)) * 8, \
               &Vs[BUF][32 * w + 8 * j][0]);                                  \
    }                                                                         \
  }

  // prologue: stage tiles 0 (and 1), K frag 0; counted wait leaves tile 1 in flight
  STAGE_V(0, 0);
  V16 kf; kf.v = *(const u32x4*)kptr;        // K frag for tile 0
  PIN();                                     // keep kf load older than stage 1
  if (qt >= 1) {
    STAGE_V(64, 1);
    asm volatile("s_waitcnt vmcnt(4)" ::: "memory");
  } else {
    asm volatile("s_waitcnt vmcnt(0)" ::: "memory");
  }
  PIN();
  __builtin_amdgcn_s_barrier();
  PIN();

  for (int t = 0; t <= qt; ++t) {
    const int cur = t % 3;

    V16 kfn;
    if (t < qt) {                            // prefetch next K frag (oldest VMEM)
      kptr += (size_t)64 * LD;
      kfn.v = *(const u32x4*)kptr;
    }
    PIN();                                   // pin kfn before the stage DMA
    if (t + 2 <= qt) STAGE_V((t + 2) * 64, (t + 2) % 3);

    // wave-uniform: does this wave's kv sub-block exist under the causal mask?
    const bool live = (t < qt) | (kvp <= qsub);
    if (live) {
      // S^T[kv][q] in one MFMA: col = lane&31 = q, row kv = (r&3)+8*(r>>2)+4*hi
      f32x16 st = __builtin_amdgcn_mfma_f32_32x32x16_bf16(kf.s, bq.s, z16, 0, 0, 0);
      const int kv0 = t * 64 + kvp * 32;
      const bool diag = (t == qt) & (kvp == qsub);
      float pr[16];
      if (diag) {
#pragma unroll
        for (int r = 0; r < 16; ++r) {
          float s = st[r];
          float a = fmaf(s, fmaf(s, 0.03125f, 0.25f), 1.0f);
          const int kvr = kv0 + (r & 3) + 8 * (r >> 2) + 4 * hi;
          a = (kvr <= q_abs) ? a : 0.0f;
          zcA[r & 3] += a; pr[r] = a;
        }
      } else {
#pragma unroll
        for (int r = 0; r < 16; ++r) {
          float s = st[r];
          float a = fmaf(s, fmaf(s, 0.03125f, 0.25f), 1.0f);
          zcA[r & 3] += a; pr[r] = a;
        }
      }

      // P -> two PV A-frags (kv 0..15 / 16..31) via cvt_pk + permlane32_swap
      union PA { short8 s; unsigned int wd[4]; } pa0, pa1;
      {
        unsigned int x0 = pkbf(pr[0], pr[1]), x1 = pkbf(pr[2], pr[3]);
        unsigned int y0 = pkbf(pr[4], pr[5]), y1 = pkbf(pr[6], pr[7]);
        plswap(x0, y0); plswap(x1, y1);
        pa0.wd[0] = x0; pa0.wd[1] = x1; pa0.wd[2] = y0; pa0.wd[3] = y1;
      }
      {
        unsigned int x0 = pkbf(pr[8], pr[9]),  x1 = pkbf(pr[10], pr[11]);
        unsigned int y0 = pkbf(pr[12], pr[13]), y1 = pkbf(pr[14], pr[15]);
        plswap(x0, y0); plswap(x1, y1);
        pa1.wd[0] = x0; pa1.wd[1] = x1; pa1.wd[2] = y0; pa1.wd[3] = y1;
      }

      // PV: B[k=kv][n=hd] frags from swizzled Vs; 8 MFMAs, 2 chained per nc
      __builtin_amdgcn_s_setprio(1);
#pragma unroll
      for (int nc = 0; nc < 4; ++nc) {
        const int hd = nc * 32 + col;
        V16 v0, v1;
        v0.v = *(const u32x4*)&Vs[cur][hd][(((kvp * 4 + hi)     ^ (hd & 7)) * 8)];
        v1.v = *(const u32x4*)&Vs[cur][hd][(((kvp * 4 + 2 + hi) ^ (hd & 7)) * 8)];
        oacc[nc] = __builtin_amdgcn_mfma_f32_32x32x16_bf16(pa0.s, v0.s, oacc[nc], 0, 0, 0);
        oacc[nc] = __builtin_amdgcn_mfma_f32_32x32x16_bf16(pa1.s, v1.s, oacc[nc], 0, 0, 0);
      }
      __builtin_amdgcn_s_setprio(0);
    }
    // counted boundary wait: t+1's stage (+kfn) landed; t+2's may stay in flight
    if (t + 2 <= qt) {
      asm volatile("s_waitcnt vmcnt(4)" ::: "memory");
    } else {
      asm volatile("s_waitcnt vmcnt(0)" ::: "memory");
    }
    PIN();
    __builtin_amdgcn_s_barrier();
    PIN();
    if (t < qt) kf = kfn;
  }

  // z: merge split chains, then lane + lane^32 (rows 4..7 offset half)
  float zcol = (zcA[0] + zcA[1]) + (zcA[2] + zcA[3]);
  zcol += __shfl_xor(zcol, 32, 64);

  // combine kv-parity partials: waves 2,3 donate through LDS (reuse Vs[0..1])
  float* fbuf = (float*)&Vs[0][0][0];        // 8192 floats = 32 KB
  if (w >= 2) {
    const int base = (w & 1) * 4096;
#pragma unroll
    for (int nc = 0; nc < 4; ++nc)
#pragma unroll
      for (int g = 0; g < 4; ++g) {
        f32x4 v = {oacc[nc][4 * g], oacc[nc][4 * g + 1],
                   oacc[nc][4 * g + 2], oacc[nc][4 * g + 3]};
        *(f32x4*)&fbuf[base + ((nc * 4 + g) * 64 + lane) * 4] = v;
      }
    if (lane < 32) zbuf[w & 1][lane] = zcol;
  }
  __syncthreads();
  if (w < 2) {
    const int base = w * 4096;
#pragma unroll
    for (int nc = 0; nc < 4; ++nc)
#pragma unroll
      for (int g = 0; g < 4; ++g) {
        f32x4 v = *(const f32x4*)&fbuf[base + ((nc * 4 + g) * 64 + lane) * 4];
#pragma unroll
        for (int r = 0; r < 4; ++r) oacc[nc][4 * g + r] += v[r];
      }
    const float zinv = 1.0f / (zcol + zbuf[w][col] + 1e-12f);
    // D[q][hd]: col = lane&31 = hd-offset, row q = (r&3)+8*(r>>2)+4*hi
#pragma unroll
    for (int g = 0; g < 4; ++g)
#pragma unroll
      for (int rr = 0; rr < 4; ++rr) {
        const int qrow = rr + 8 * g + 4 * hi;
        const float iv = __shfl(zinv, qrow, 64);
        const size_t base_o = (size_t)(b * 2048 + q0 + qrow) * 1536 + h * 128 + col;
#pragma unroll
        for (int nc = 0; nc < 4; ++nc)
          obuf[base_o + nc * 32] = f2bf(oacc[nc][4 * g + rr] * iv);
      }
  }
#undef STAGE_V
}

// ---- launch -----------------------------------------------------------
extern "C" void kernel_launch(void* const* d_in, const int* in_sizes, int n_in,
                              void* d_out, int out_size, void* d_ws, size_t ws_size,
                              hipStream_t stream) {
  const void* hs = d_in[0];
  const void* Wq = d_in[1];
  const void* Wk = d_in[2];
  const void* Wv = d_in[3];
  const void* Wo = d_in[4];
  const unsigned short* hsp = (const unsigned short*)hs;

  // ws (~39 MB): WT[1920][1536] | WoT[1536][1536] | qkvb[4096][384]
  //              | hsb[4096][1536] | vT[24*128][2048]
  unsigned short* ws   = (unsigned short*)d_ws;
  unsigned short* WT   = ws;                        // q 0..191, k 192..383, v 384..1919
  unsigned short* WoT  = WT + 1920 * 1536;
  unsigned short* qkvb = WoT + 1536 * 1536;         // compact q|k only, ld=384
  unsigned short* hsb  = qkvb + 4096 * 384;
  unsigned short* vT   = hsb + 4096 * 1536;
  unsigned short* obuf = hsb;                       // hsb dead after qkv gemm

  // weights transpose + hs convert, one dispatch
  w_tr<<<dim3(24, 128, 5), 256, 0, stream>>>(Wq, Wk, Wv, Wo, hs, WT, WoT, hsb);

  // fused q|k|v projection: qk -> qkvb (ld 384); v -> vT transposed (fused)
  gemm_bt<<<dim3(15, 32, 1), 256, 0, stream>>>(hsb, WT, qkvb, 4096, 1920, 1536,
                                               384, vT, nullptr);

  // fused causal based-attention (32x32 swapped-QK^T, ring-3 counted vmcnt)
  attn_based<<<dim3(24, 32, 1), 256, 0, stream>>>(qkvb, vT, obuf);

  // output projection -> d_out (fp32 store iff inputs were fp32)
  gemm_bt<<<dim3(12, 32, 1), 256, 0, stream>>>(obuf, WoT, d_out, 4096, 1536, 1536,
                                               1536, nullptr, hsp);
}